// Round 7
// baseline (203.337 us; speedup 1.0000x reference)
//
#include <hip/hip_runtime.h>
#include <cstdint>

#define CONF_THRES 0.25f
#define IOU_THRES  0.45f
#define MAX_DET    300
#define K_TOP      8192
#define NA         102000
#define NCLS       80
#define ROWLEN     85
#define CAP        32640
#define NPLANE     4
#define NBINS      16384        // scores < 1.0 -> sb>>16 < 0x3f80 < 16384
#define WIN        512
#define NWIN       (K_TOP / WIN)
#define SSTR       9            // LDS row stride in u64 (pad 8->9: bank spread)

typedef unsigned long long u64;
typedef unsigned int u32;

// ---------------- kernel 0: zero meta+remw+sorted + rankArr + hist planes ---------
__global__ __launch_bounds__(256) void zero_kernel(uint4* __restrict__ a,
        uint4* __restrict__ r, uint4* __restrict__ b) {
    int i = blockIdx.x * 256 + threadIdx.x;          // grid 64 -> 16384 threads
    uint4 z = make_uint4(0u, 0u, 0u, 0u);
    if (i < 4164) a[i] = z;                          // meta+remw+sorted = 66624 B
    if (i < 8160) r[i] = z;                          // rankArr = 130560 B
    b[i] = z;                                        // hist planes: 16384 uint4 = 256KB
}

// ---------------- kernel 1: wave-per-anchor -> keys + histogram + packed record ----
// Round-7: emits per-anchor 32B record {ymin,xmin,ymax,xmax, score,cls,area,0} so
// the gather becomes a trivial 32B copy (no preds re-read, no per-candidate wave
// reduce). Class/score use the exact packed (bits(q)<<8 | 255-cls) max that the
// old gather used -> identical argmax/tie-break/rounding. score = (obj>CONF) ?
// max_q : 0 (max over fl(p*obj) == fl(max p * obj) by monotonicity, and the
// packed max IS max_q bit-exactly).
__global__ __launch_bounds__(256) void score_key_kernel(const float* __restrict__ preds,
        u64* __restrict__ keys, u32* __restrict__ histP, float4* __restrict__ recs) {
#pragma clang fp contract(off)
    int lane = threadIdx.x & 63;
    int i = blockIdx.x * 4 + (threadIdx.x >> 6);     // 4 waves/block, 1 anchor/wave
    if (i >= NA) return;
    const float* p = preds + (size_t)i * ROWLEN;
    float v0 = p[lane];                               // offsets 0..63
    float v1 = (lane < ROWLEN - 64) ? p[64 + lane] : 0.0f; // offsets 64..84
    float obj = __shfl(v0, 4);
    u64 kb = 0;
    if (lane >= 5) {                                  // classes 0..58
        float q = v0 * obj;
        kb = ((u64)__float_as_uint(q) << 8) | (u32)(255 - (lane - 5));
    }
    if (lane < 21) {                                  // classes 59..79
        float q = v1 * obj;
        u64 kb2 = ((u64)__float_as_uint(q) << 8) | (u32)(255 - (59 + lane));
        if (kb2 > kb) kb = kb2;
    }
    for (int off = 32; off; off >>= 1) {
        u64 o = __shfl_xor(kb, off);
        if (o > kb) kb = o;
    }
    float x = __shfl(v0, 0), y = __shfl(v0, 1);
    float w = __shfl(v0, 2), h = __shfl(v0, 3);
    if (lane == 0) {
        float maxq = __uint_as_float((u32)(kb >> 8));
        float score = (obj > CONF_THRES) ? maxq : 0.0f;
        u32 sb = __float_as_uint(score);
        u32 cls = 255u - (u32)(kb & 0xffull);
        float ymin = y - h * 0.5f, xmin = x - w * 0.5f;
        float ymax = y + h * 0.5f, xmax = x + w * 0.5f;
        keys[i] = ((u64)sb << 32) | (u32)(~(u32)i);
        recs[2 * i]     = make_float4(ymin, xmin, ymax, xmax);
        recs[2 * i + 1] = make_float4(score, (float)cls,
                                      (ymax - ymin) * (xmax - xmin), 0.0f);
        if (sb != 0u)
            atomicAdd(&histP[((u32)blockIdx.x & (NPLANE - 1u)) * NBINS + (sb >> 16)], 1u);
    }
}

// ---------------- kernel 2: threshold bucket for top-K (reads 4 planes inline) -----
__global__ __launch_bounds__(1024) void cutoff_kernel(const u32* __restrict__ histP,
        u32* __restrict__ meta) {
    __shared__ u32 suf[1024];
    __shared__ int cbs;
    __shared__ u32 above_s;
    int t = threadIdx.x;
    u32 s = 0;
    for (int r = 0; r < NPLANE; ++r) {
        const u32* hb = histP + r * NBINS + t * 16;   // 1024 chunks x 16 bins
        for (int b = 0; b < 16; ++b) s += hb[b];
    }
    suf[t] = s;
    if (t == 0) { cbs = -1; above_s = 0; }
    __syncthreads();
    for (int off = 1; off < 1024; off <<= 1) {
        u32 add = (t + off < 1024) ? suf[t + off] : 0u;
        __syncthreads();
        suf[t] += add;
        __syncthreads();
    }
    u32 st = suf[t];
    u32 stn = (t < 1023) ? suf[t + 1] : 0u;
    if (st >= (u32)K_TOP && stn < (u32)K_TOP) {       // at most one thread
        cbs = t;
        above_s = stn;                                 // sum of chunks above cb
    }
    __syncthreads();
    int cb = cbs;
    if (t < 64) {                                      // wave 0 does the fine pass
        u32 thresh = 0;
        if (cb >= 0) {
            u32 above = above_s;
            u32 v = 0;
            if (t < 16) {
                for (int r = 0; r < NPLANE; ++r) v += histP[r * NBINS + cb * 16 + t];
            }
            for (int off = 1; off < 64; off <<= 1) {
                u32 o = __shfl_down(v, off);
                if (t + off < 64) v += o;
            }
            u64 bal = __ballot(v + above >= (u32)K_TOP);
            int bstar = 63 - __builtin_clzll((unsigned long long)bal);
            thresh = ((u32)(cb * 16 + bstar)) << 16;
        }
        if (t == 0) meta[1] = thresh;                  // meta[0] zeroed by zero_kernel
    }
}

// ---------------- kernel 3: compact candidates above threshold ----------------
__global__ __launch_bounds__(256) void compact_kernel(const u64* __restrict__ keys,
        u32* __restrict__ meta, u64* __restrict__ comp) {
    __shared__ u32 woff[4];
    __shared__ u32 bbase;
    int i = blockIdx.x * 256 + threadIdx.x;
    int wid = threadIdx.x >> 6, lane = threadIdx.x & 63;
    u64 key = (i < NA) ? keys[i] : 0ull;
    u32 sb = (u32)(key >> 32);
    u32 th = meta[1];
    bool take = (i < NA) && (sb != 0u) && (sb >= th);
    u64 bal = __ballot(take);
    if (lane == 0) woff[wid] = (u32)__popcll(bal);
    __syncthreads();
    if (threadIdx.x == 0) {
        u32 t0 = woff[0], t1 = woff[1], t2 = woff[2], t3 = woff[3];
        bbase = atomicAdd(&meta[0], t0 + t1 + t2 + t3);
        woff[0] = 0; woff[1] = t0; woff[2] = t0 + t1; woff[3] = t0 + t1 + t2;
    }
    __syncthreads();
    if (take) {
        u32 pos = bbase + woff[wid] + (u32)__popcll(bal & ((1ull << lane) - 1ull));
        if (pos < CAP) comp[pos] = key;
    }
}

// ---------------- kernel 4a: 2-D partial rank-by-counting ----------------
__global__ __launch_bounds__(256) void rank_partial_kernel(const u64* __restrict__ comp,
        const u32* __restrict__ meta, u32* __restrict__ rankArr) {
    __shared__ u64 tile[1024];
    u32 cnt = meta[0];
    int n = (int)(cnt < (u32)CAP ? cnt : (u32)CAP);
    int i0 = blockIdx.x * 256;
    int j0 = blockIdx.y * 1024;
    if (i0 >= n || j0 >= n) return;                  // uniform early exit
    int lim = n - j0; if (lim > 1024) lim = 1024;
    for (int k = threadIdx.x; k < 1024; k += 256)
        tile[k] = (k < lim) ? comp[j0 + k] : 0ull;
    __syncthreads();
    int i = i0 + threadIdx.x;
    if (i < n) {
        u64 key = comp[i];
        u32 r = 0;
#pragma unroll 8
        for (int j = 0; j < 1024; ++j) r += (tile[j] > key) ? 1u : 0u;
        atomicAdd(&rankArr[i], r);
    }
}

// ---------------- kernel 4b: scatter keys to their rank ----------------
__global__ __launch_bounds__(256) void scatter_kernel(const u64* __restrict__ comp,
        const u32* __restrict__ meta, const u32* __restrict__ rankArr,
        u64* __restrict__ sorted) {
    u32 cnt = meta[0];
    int n = (int)(cnt < (u32)CAP ? cnt : (u32)CAP);
    int i = blockIdx.x * 256 + threadIdx.x;
    if (i < n) {
        u32 r = rankArr[i];
        if (r < (u32)K_TOP) sorted[r] = comp[i];     // keys unique -> permutation
    }
}

// ---------------- kernel 5: thread-per-candidate gather (32B record copy) ----------
__global__ __launch_bounds__(256) void gather_kernel(const u64* __restrict__ sorted,
        const float4* __restrict__ recs, float* __restrict__ boxes,
        float* __restrict__ scores, float* __restrict__ classes,
        float* __restrict__ areas) {
    int i = blockIdx.x * 256 + threadIdx.x;          // grid 32 -> 8192
    u64 key = sorted[i];
    u32 sb = (u32)(key >> 32);
    float score = __uint_as_float(sb);
    float4 b = make_float4(0.0f, 0.0f, 0.0f, 0.0f);
    float c = 0.0f, a = 0.0f;
    if (score > 0.0f) {
        u32 idx = ~(u32)(key & 0xffffffffull);
        float4 r0 = recs[2 * idx];
        float4 r1 = recs[2 * idx + 1];
        b = r0; c = r1.y; a = r1.z;
    }
    ((float4*)boxes)[i] = b;
    scores[i] = score;
    classes[i] = c;
    areas[i] = a;
}

// ---------------- kernel 6: suppression bitmask, 2 rows per lane ----------------
// Round-7: 128-row x 256-col blocks; each lane owns 2 rows so one cb/ca LDS
// broadcast pair per k serves two IoUs (halves LDS pipe cost). Divide replaced
// bit-exactly by f64 multiply-compare (round-5, proven). Valid ballots fused.
// Below-diagonal blocks/waves skipped; their words are never read by the scan
// (fold rows strictly upper, diag-window reads only at/above the diagonal word).
__global__ __launch_bounds__(256) void mask_kernel(const float* __restrict__ boxes,
        const float* __restrict__ areas, const float* __restrict__ scores,
        u64* __restrict__ mask, u64* __restrict__ remw) {
#pragma clang fp contract(off)
    int cx = blockIdx.x;                 // col tile: 256 cols = words [cx*4, cx*4+4)
    int ry = blockIdx.y;                 // row tile: rows [ry*128, ry*128+128)
    int wr0 = ry * 2;                    // first word-row of this tile
    if (cx * 4 + 3 < wr0) return;        // fully below diagonal: never read
    __shared__ float4 cb[256];           // column boxes
    __shared__ float  ca[256];           // column areas
    __shared__ u64 st[128 * 5];          // [row][word], stride 5 (bank spread)
    int tid = threadIdx.x;
    int wv = tid >> 6, lane = tid & 63;
    int r0 = ry * 128;
    int jw = cx * 4 + wv;                // this wave's column word
    cb[tid] = ((const float4*)boxes)[cx * 256 + tid];   // coalesced col stage
    ca[tid] = areas[cx * 256 + tid];
    if (jw == wr0) {                     // fused valid: one wave per word-row
        u64 b = __ballot(scores[r0 + lane] > 0.0f);
        if (lane == 0) remw[wr0] = b;
    }
    if (jw == wr0 + 1) {
        u64 b = __ballot(scores[r0 + 64 + lane] > 0.0f);
        if (lane == 0) remw[wr0 + 1] = b;
    }
    __syncthreads();
    u64 wA = 0, wB = 0;
    if (jw >= wr0) {                     // below-diag waves: zeros
        float4 biA = ((const float4*)boxes)[r0 + lane];
        float aiA = areas[r0 + lane];
        float4 biB = ((const float4*)boxes)[r0 + 64 + lane];
        float aiB = areas[r0 + 64 + lane];
        const double Bd = (double)IOU_THRES + 0x1p-26;  // fl32(x)>T <=> x>Bd
        int kb = wv * 64;
#pragma unroll
        for (int k = 0; k < 64; ++k) {
            float4 bj = cb[kb + k];      // all lanes same addr -> LDS broadcast
            float aj = ca[kb + k];
            // row set A
            float tyA = fmaxf(biA.x, bj.x);
            float txA = fmaxf(biA.y, bj.y);
            float byA = fminf(biA.z, bj.z);
            float bxA = fminf(biA.w, bj.w);
            float inA = fmaxf(byA - tyA, 0.0f) * fmaxf(bxA - txA, 0.0f);
            float uA = ((aiA + aj) - inA) + 1e-9f;
            wA |= ((double)inA > Bd * (double)uA) ? (1ull << k) : 0ull;
            // row set B
            float tyB = fmaxf(biB.x, bj.x);
            float txB = fmaxf(biB.y, bj.y);
            float byB = fminf(biB.z, bj.z);
            float bxB = fminf(biB.w, bj.w);
            float inB = fmaxf(byB - tyB, 0.0f) * fmaxf(bxB - txB, 0.0f);
            float uB = ((aiB + aj) - inB) + 1e-9f;
            wB |= ((double)inB > Bd * (double)uB) ? (1ull << k) : 0ull;
        }
        if (jw == wr0)                   // diag word for set A
            wA &= (lane < 63) ? (~0ull << (lane + 1)) : 0ull;
        if (jw < wr0 + 1) {              // set B needs jw >= wr0+1
            if (jw == wr0) wB = 0;       // (jw < wr0 unreachable here)
        }
        if (jw == wr0 + 1)               // diag word for set B
            wB &= (lane < 63) ? (~0ull << (lane + 1)) : 0ull;
    }
    st[lane * 5 + wv] = wA;
    st[(lane + 64) * 5 + wv] = wB;
    __syncthreads();
#pragma unroll
    for (int q = 0; q < 2; ++q) {        // flush 512 words coalesced
        int idx = q * 256 + tid;
        int rr = idx >> 2, ww = idx & 3;
        mask[(size_t)(r0 + rr) * 128 + cx * 4 + ww] = st[rr * 5 + ww];
    }
}

// ---------------- kernel 7: pipelined greedy scan (4 waves, double-buffered) -------
__device__ __forceinline__ u64 rfl64(u64 v) {
    u32 lo = (u32)__builtin_amdgcn_readfirstlane((int)(u32)v);
    u32 hi = (u32)__builtin_amdgcn_readfirstlane((int)(u32)(v >> 32));
    return ((u64)hi << 32) | lo;
}

__device__ __forceinline__ u64 bcast64(u64 v, int srclane) {
    u32 lo = (u32)__builtin_amdgcn_readlane((int)(u32)v, srclane);
    u32 hi = (u32)__builtin_amdgcn_readlane((int)(u32)(v >> 32), srclane);
    return ((u64)hi << 32) | lo;
}

__device__ __forceinline__ u64 shfl_xor64(u64 v, int m) {
    u32 lo = __shfl_xor((u32)v, m, 64);
    u32 hi = __shfl_xor((u32)(v >> 32), m, 64);
    return ((u64)hi << 32) | lo;
}

__global__ __launch_bounds__(256) void nms_scan_kernel(const u64* __restrict__ mask,
        const u64* __restrict__ remw, const float* __restrict__ boxes,
        const float* __restrict__ scores, const float* __restrict__ classes,
        float* __restrict__ out) {
    __shared__ u64 sub[2][WIN * SSTR];                // 2 x 36 KB double buffer
    __shared__ u64 accW[4][8];                        // per-wave fold partials
    __shared__ u32 ki[MAX_DET + 8];                   // kept indices (ascending)
    __shared__ int n_sh;
    int tid = threadIdx.x;
    int wid = tid >> 6, lane = tid & 63;
    if (tid == 0) n_sh = 0;
#pragma unroll
    for (int it = 0; it < 8; ++it) {
        int idx = it * 256 + tid;                     // 2048 uint4
        int r = idx >> 2, j = (idx & 3) * 2;
        uint4 v = *(const uint4*)&mask[(size_t)r * 128 + j];
        sub[0][r * SSTR + j]     = ((u64)v.y << 32) | v.x;
        sub[0][r * SSTR + j + 1] = ((u64)v.w << 32) | v.z;
    }
    __syncthreads();
    int n = 0;
    for (int win = 0; win < NWIN; ++win) {
        if (n >= MAX_DET) break;                      // uniform
        int rbase = win * WIN;
        int cb = win & 1;
        u64 acc[8] = {0, 0, 0, 0, 0, 0, 0, 0};
        for (int m = tid; m < n; m += 256) {
            int k = (int)ki[m];
            const u64* rp = &mask[(size_t)k * 128 + win * 8];
#pragma unroll
            for (int j = 0; j < 8; ++j) acc[j] |= rp[j];
        }
#pragma unroll
        for (int j = 0; j < 8; ++j)
            for (int off = 32; off; off >>= 1) acc[j] |= shfl_xor64(acc[j], off);
        if (lane == 0) {
#pragma unroll
            for (int j = 0; j < 8; ++j) accW[wid][j] = acc[j];
        }
        __syncthreads();
        if (wid != 0) {
            if (win + 1 < NWIN) {                     // stage NEXT window
                int t = tid - 64;                     // 0..191
                for (int it = 0; it < 11; ++it) {
                    int idx = it * 192 + t;
                    if (idx < 2048) {
                        int r = idx >> 2, j = (idx & 3) * 2;
                        uint4 v = *(const uint4*)&mask[
                                (size_t)(rbase + WIN + r) * 128 + (win + 1) * 8 + j];
                        sub[cb ^ 1][r * SSTR + j]     = ((u64)v.y << 32) | v.x;
                        sub[cb ^ 1][r * SSTR + j + 1] = ((u64)v.w << 32) | v.z;
                    }
                }
            }
        } else {
            u64 diag[8];
#pragma unroll
            for (int sw = 0; sw < 8; ++sw)
                diag[sw] = sub[cb][(sw * 64 + lane) * SSTR + sw];
            int n0 = n;
            u64 keptW[8] = {0, 0, 0, 0, 0, 0, 0, 0};
#pragma unroll
            for (int sw = 0; sw < 8; ++sw) {
                if (n < MAX_DET) {
                    u64 acc2 = 0;
#pragma unroll
                    for (int wp = 0; wp < 8; ++wp) {
                        if (wp < sw) {
                            if ((keptW[wp] >> lane) & 1ull)
                                acc2 |= sub[cb][(wp * 64 + lane) * SSTR + sw];
                        }
                    }
                    for (int off = 32; off; off >>= 1) acc2 |= shfl_xor64(acc2, off);
                    u64 afold = accW[0][sw] | accW[1][sw] | accW[2][sw] | accW[3][sw];
                    u64 cur = rfl64(remw[win * 8 + sw]) & ~rfl64(afold) & ~rfl64(acc2);
                    u64 kw = 0;
                    while (cur != 0ull && n < MAX_DET) {  // uniform scalar pop chain
                        int b = __ffsll((unsigned long long)cur) - 1;
                        u64 slice = bcast64(diag[sw], b);
                        kw |= (1ull << b);
                        cur &= ~(slice | (1ull << b));
                        ++n;
                    }
                    keptW[sw] = kw;
                }
            }
            int base = n0;
#pragma unroll
            for (int sw = 0; sw < 8; ++sw) {
                u64 kw = keptW[sw];
                if ((kw >> lane) & 1ull) {
                    int rr = (int)__popcll(kw & ((1ull << lane) - 1ull));
                    ki[base + rr] = (u32)(rbase + sw * 64 + lane);
                }
                base += (int)__popcll(kw);
            }
            if (lane == 0) n_sh = n;
        }
        __syncthreads();                              // staging + pop + ki complete
        n = n_sh;
    }
    __syncthreads();
    for (int m = tid; m < MAX_DET; m += 256) {
        float4 b = make_float4(0.0f, 0.0f, 0.0f, 0.0f);
        float c = 0.0f, s = 0.0f;
        if (m < n) {
            int k = (int)ki[m];
            b = ((const float4*)boxes)[k];
            c = classes[k];
            s = scores[k];
        }
        ((float4*)out)[m] = b;
        out[1200 + m] = c;
        out[1500 + m] = s;
    }
}

// ---------------- launch ----------------
extern "C" void kernel_launch(void* const* d_in, const int* in_sizes, int n_in,
                              void* d_out, int out_size, void* d_ws, size_t ws_size,
                              hipStream_t stream) {
    const float* preds = (const float*)d_in[0];
    char* ws = (char*)d_ws;

    // ws layout (bytes), total 9991104:
    //   [65536, 196096)        rankArr     u32[32640] (zeroed up-front)
    //   [262144, 262208)       meta        u32[16]   ([0]=counter, [1]=thresh)
    //   [262208, 263232)       remw        u64[128]
    //   [263232, 328768)       sorted      u64[8192]
    //   [328768, 1144768)      keys        u64[102000] (dead after compact)
    //   [1144768, 1405888)     comp        u64[32640] (dead after scatter;
    //                                      front 32768 B reused as tareas)
    //   [1405888, 1536960)     top_boxes   f32[8192*4]
    //   [1536960, 1569728)     top_scores  f32[8192]
    //   [1569728, 1602496)     top_classes f32[8192]
    //   [1602496, 9991104)     mask        u64[8192*128]  (8 MB; front 256 KiB
    //                                      doubles as 4x16384 hist planes, and
    //                                      [2126784, 5390784) as recs float4[2*NA]
    //                                      — both dead before mask_kernel writes)
    u32*   rankArr = (u32*)(ws + 65536);
    u32*   meta    = (u32*)(ws + 262144);
    u64*   remw    = (u64*)(ws + 262208);
    u64*   sorted  = (u64*)(ws + 263232);
    u64*   keys    = (u64*)(ws + 328768);
    u64*   comp    = (u64*)(ws + 1144768);
    float* tareas  = (float*)(ws + 1144768);         // aliases comp (dead by gather)
    float* tboxes  = (float*)(ws + 1405888);
    float* tscores = (float*)(ws + 1536960);
    float* tclass  = (float*)(ws + 1569728);
    u64*   mask    = (u64*)(ws + 1602496);
    u32*   histP   = (u32*)(ws + 1602496);           // aliases mask front (earlier)
    float4* recs   = (float4*)(ws + 2126784);        // aliases mask mid (earlier)
    float* out     = (float*)d_out;

    zero_kernel<<<64, 256, 0, stream>>>((uint4*)(ws + 262144), (uint4*)rankArr,
            (uint4*)histP);
    score_key_kernel<<<(NA + 3) / 4, 256, 0, stream>>>(preds, keys, histP, recs);
    cutoff_kernel<<<1, 1024, 0, stream>>>(histP, meta);
    compact_kernel<<<(NA + 255) / 256, 256, 0, stream>>>(keys, meta, comp);
    rank_partial_kernel<<<dim3((CAP + 255) / 256, (CAP + 1023) / 1024), 256, 0, stream>>>(
            comp, meta, rankArr);
    scatter_kernel<<<(CAP + 255) / 256, 256, 0, stream>>>(comp, meta, rankArr, sorted);
    gather_kernel<<<K_TOP / 256, 256, 0, stream>>>(sorted, recs, tboxes, tscores,
            tclass, tareas);
    mask_kernel<<<dim3(32, 64), 256, 0, stream>>>(tboxes, tareas, tscores, mask, remw);
    nms_scan_kernel<<<1, 256, 0, stream>>>(mask, remw, tboxes, tscores, tclass, out);
}